// Round 1
// 428.914 us; speedup vs baseline: 1.0465x; 1.0465x over previous
//
#include <hip/hip_runtime.h>
#include <cstdint>
#include <cstddef>

typedef unsigned short u16;
typedef __attribute__((ext_vector_type(8))) short s16x8;      // 8 bf16 = 4 VGPRs (MFMA A/B frag)
typedef __attribute__((ext_vector_type(8))) unsigned short u16x8;
typedef __attribute__((ext_vector_type(4))) float f32x4;      // MFMA C/D frag / float4 load

#define D_MODEL 1024
#define DH 64
#define BS 256
// B*S = 16384 tokens, 64 blocks of 256, 16 heads. External tensors are FLOAT32; internal bf16.

__device__ __forceinline__ u16 f2bf(float f) {
  union { float f; unsigned int i; } x; x.f = f;
  unsigned int r = x.i + 0x7fffu + ((x.i >> 16) & 1u);   // RNE
  return (u16)(r >> 16);
}

__device__ __forceinline__ void gl_lds16(const u16* g, u16* l) {
  __builtin_amdgcn_global_load_lds((const __attribute__((address_space(1))) void*)g,
                                   (__attribute__((address_space(3))) void*)l, 16, 0, 0);
}

// ---------------- cast x: f32 -> bf16, 16.7M elems ----------------
__global__ __launch_bounds__(256) void cast_x(const float* __restrict__ x, u16* __restrict__ xb) {
  int i = (blockIdx.x * 256 + threadIdx.x) * 8;
  f32x4 a0 = *(const f32x4*)(x + i);
  f32x4 a1 = *(const f32x4*)(x + i + 4);
  u16x8 v;
#pragma unroll
  for (int j = 0; j < 4; ++j) { v[j] = f2bf(a0[j]); v[j + 4] = f2bf(a1[j]); }
  *(u16x8*)(xb + i) = v;
}

// ---------------- W transpose+cast: Wt[n][k] = bf16(W[k][n]) (1024x1024 f32 -> bf16, x4) ----------------
__global__ __launch_bounds__(256) void transpose_w(const float* __restrict__ w0,
                                                   const float* __restrict__ w1,
                                                   const float* __restrict__ w2,
                                                   const float* __restrict__ w3,
                                                   u16* __restrict__ out) {
  __shared__ u16 tile[64][65];
  const int z = blockIdx.z;
  const float* W = (z == 0) ? w0 : (z == 1) ? w1 : (z == 2) ? w2 : w3;
  u16* O = out + (size_t)z * (D_MODEL * D_MODEL);
  const int kb = blockIdx.y * 64, nb = blockIdx.x * 64;
  const int t = threadIdx.x;
#pragma unroll
  for (int i = 0; i < 16; ++i) {
    int e = i * 256 + t;
    int r = e >> 6, c = e & 63;
    tile[r][c] = f2bf(W[(size_t)(kb + r) * D_MODEL + nb + c]);
  }
  __syncthreads();
#pragma unroll
  for (int i = 0; i < 16; ++i) {
    int e = i * 256 + t;
    int r = e >> 6, c = e & 63;
    O[(size_t)(nb + r) * D_MODEL + kb + c] = tile[c][r];
  }
}

// ================= 256x256 8-phase GEMM (m201 template, plain HIP) =================
// BM=BN=256, BK=64, 512 threads = 8 waves (2M x 4N), per-wave C = 128x64.
// LDS 128 KiB: As[2][256][64], Bs[2][256][64] bf16, double-buffered.
// st_16x32 swizzle: byte ^= ((byte>>9)&1)<<5  (== u16off ^= (row&4)<<2 for 128B rows).
//   Applied as: linear global_load_lds DEST + inverse-swizzled global SOURCE + swizzled ds_read.
// Half-tile issue order (B0,B1,A0,A1); per K-tile: P1 stages last half of tile t+1 (buf^1),
// P2..P4 stage B0,B1,A0 of tile t+2 (buf cur) — each targets a region whose reads finished
// >=1 phase before the ~200cy+ load-return can land. vmcnt(6) once per K-tile (phase 4).

#define TIU 16384   // u16 per 256x64 buffer
#define HIU 8192    // u16 per 128x64 half-tile

__device__ __forceinline__ void stage_half(const u16* __restrict__ src, int rowG0, int k0,
                                           u16* ldst, int tid) {
#pragma unroll
  for (int i = 0; i < 2; ++i) {
    int c = i * 512 + tid;                       // linear 16B chunk in half-tile
    int cs = c ^ (((c >> 5) & 1) << 1);          // inverse st_16x32 swizzle (involution)
    gl_lds16(src + (size_t)(rowG0 + (cs >> 3)) * D_MODEL + k0 + (cs & 7) * 8,
             ldst + c * 8);
  }
}

#define NOPX ((void)0)
#define BARX() __builtin_amdgcn_s_barrier()
#define VMW(N) asm volatile("s_waitcnt vmcnt(" #N ")" ::: "memory")

#define LDA8(P, MH) do { \
  _Pragma("unroll") for (int mt = 0; mt < 4; ++mt) \
  _Pragma("unroll") for (int kk = 0; kk < 2; ++kk) \
    a[mt][kk] = *(const s16x8*)(As + (P) * TIU + (arow + (MH) * 64 + mt * 16) * 64 + kk * 32 + qx); \
} while (0)

#define LDB4(P, NH) do { \
  _Pragma("unroll") for (int nt = 0; nt < 2; ++nt) \
  _Pragma("unroll") for (int kk = 0; kk < 2; ++kk) \
    b[NH][nt][kk] = *(const s16x8*)(Bs + (P) * TIU + (brow + (NH) * 32 + nt * 16) * 64 + kk * 32 + qx); \
} while (0)

#define MF16(MH, NH) do { \
  __builtin_amdgcn_s_setprio(1); \
  _Pragma("unroll") for (int kk = 0; kk < 2; ++kk) \
  _Pragma("unroll") for (int mt = 0; mt < 4; ++mt) \
  _Pragma("unroll") for (int nt = 0; nt < 2; ++nt) \
    acc[(MH) * 4 + mt][(NH) * 2 + nt] = __builtin_amdgcn_mfma_f32_16x16x32_bf16( \
        a[mt][kk], b[NH][nt][kk], acc[(MH) * 4 + mt][(NH) * 2 + nt], 0, 0, 0); \
  __builtin_amdgcn_s_setprio(0); \
} while (0)

#define STA(T, H) stage_half(A, rowBase + (H) * 128, (T) * 64, As + ((T) & 1) * TIU + (H) * HIU, t)
#define STB(T, H) stage_half(W, colBase + (H) * 128, (T) * 64, Bs + ((T) & 1) * TIU + (H) * HIU, t)

// One K-tile = 4 phases; quadrant order (0,0),(0,1),(1,1),(1,0) so B frags reload once, A once.
#define KTILE(P, S1, S2, S3, S4, WAIT) do { \
  LDA8(P, 0); LDB4(P, 0); S1; BARX(); MF16(0, 0); BARX(); \
  LDB4(P, 1);             S2; BARX(); MF16(0, 1); BARX(); \
  LDA8(P, 1);             S3; BARX(); MF16(1, 1); BARX(); \
                    S4; WAIT; BARX(); MF16(1, 0); BARX(); \
} while (0)

// MODE 0: fused QKV (bf16 out, 3 planes, N=3072). MODE 1: O-proj (f32 out, N=1024).
template <int MODE, int NCB>
__global__ __launch_bounds__(512, 2) void gemm8(
    const u16* __restrict__ A, const u16* __restrict__ W,
    const float* __restrict__ b0, const float* __restrict__ b1, const float* __restrict__ b2,
    void* __restrict__ o0, void* __restrict__ o1, void* __restrict__ o2) {
  __shared__ u16 As[2 * TIU];
  __shared__ u16 Bs[2 * TIU];

  // bijective XCD swizzle (nwg % 8 == 0 by construction: 768 / 256)
  const int nwg = gridDim.x;
  const int wg = blockIdx.x;
  const int swz = (wg & 7) * (nwg >> 3) + (wg >> 3);
  const int rowBase = (swz / NCB) * 256;
  const int colBase = (swz % NCB) * 256;

  const int t = threadIdx.x;
  const int wave = t >> 6, lane = t & 63, l15 = lane & 15, q4 = lane >> 4;
  const int wm = wave >> 2, wn = wave & 3;
  const int qx = (q4 * 8) ^ ((lane & 4) << 2);   // read-side swizzle folded into q4 offset
  const int arow = wm * 128 + l15;
  const int brow = wn * 64 + l15;

  f32x4 acc[8][4];
#pragma unroll
  for (int i = 0; i < 8; ++i)
#pragma unroll
    for (int j = 0; j < 4; ++j) acc[i][j] = {0.f, 0.f, 0.f, 0.f};

  s16x8 a[4][2];        // A frags: 4 m-tiles x 2 kk for current half
  s16x8 b[2][2][2];     // B frags: [nh][nt][kk], both halves live

  // Prologue: tile0 fully + 3 half-tiles of tile1 (issue order B0,B1,A0,A1 | B0,B1,A0)
  STB(0, 0); STB(0, 1); STA(0, 0); STA(0, 1);
  VMW(4);
  STB(1, 0); STB(1, 1); STA(1, 0);
  VMW(6);
  BARX();

#pragma unroll 1
  for (int tg = 0; tg < 14; tg += 2) {
    KTILE(0, STA(tg + 1, 1), STB(tg + 2, 0), STB(tg + 2, 1), STA(tg + 2, 0), VMW(6));
    KTILE(1, STA(tg + 2, 1), STB(tg + 3, 0), STB(tg + 3, 1), STA(tg + 3, 0), VMW(6));
  }
  // Tail: tile 14 finishes tile15's staging then drains; tile 15 computes only.
  KTILE(0, STA(15, 1), NOPX, NOPX, NOPX, VMW(0));
  KTILE(1, NOPX, NOPX, NOPX, NOPX, NOPX);

  // Epilogue: C/D map col = l15, row = q4*4 + r (verified layout)
  if constexpr (MODE == 0) {
    const int z = colBase >> 10;                 // whole block is one z-plane (256 | 1024)
    const float* bias = (z == 0) ? b0 : (z == 1) ? b1 : b2;
    u16* Out = (u16*)((z == 0) ? o0 : (z == 1) ? o1 : o2);
    const int colL = (colBase & 1023) + wn * 64;
#pragma unroll
    for (int ni = 0; ni < 4; ++ni) {
      int col = colL + ni * 16 + l15;
      float bv = bias[col];
#pragma unroll
      for (int mi = 0; mi < 8; ++mi) {
        int row0 = rowBase + wm * 128 + mi * 16 + q4 * 4;
#pragma unroll
        for (int r = 0; r < 4; ++r)
          Out[(size_t)(row0 + r) * D_MODEL + col] = f2bf(acc[mi][ni][r] + bv);
      }
    }
  } else {
    float* Out = (float*)o0;
    const int colL = colBase + wn * 64;
#pragma unroll
    for (int ni = 0; ni < 4; ++ni) {
      int col = colL + ni * 16 + l15;
      float bv = b0[col];
#pragma unroll
      for (int mi = 0; mi < 8; ++mi) {
        int row0 = rowBase + wm * 128 + mi * 16 + q4 * 4;
#pragma unroll
        for (int r = 0; r < 4; ++r)
          Out[(size_t)(row0 + r) * D_MODEL + col] = acc[mi][ni][r] + bv;
      }
    }
  }
}

// ---------------- Attention: one WG (128 thr = 2 waves) per (block n, head h) ----------------
// All causal-skip conditions are wave-uniform guards inside constant-trip unrolled loops
// (NO dynamic break: a break defeats unrolling and forces sc[] into scratch — R4 lesson).
__global__ __launch_bounds__(128) void attn(const u16* __restrict__ Q, const u16* __restrict__ K,
                                            const u16* __restrict__ V, u16* __restrict__ O) {
  __shared__ u16 vt[64 * 264];        // V^T: [d][tok], row stride 264
  __shared__ u16 pl[2 * 16 * 264];    // per-wave P / O staging: [wave][16 rows][256(+pad) cols]
  const int g = blockIdx.x;
  const int n = g >> 4, h = g & 15;
  const size_t base = (size_t)n * BS * D_MODEL + (size_t)h * DH;
  const u16* Qb = Q + base;
  const u16* Kb = K + base;
  const u16* Vb = V + base;
  u16* Ob = O + base;
  const int t = threadIdx.x, wave = t >> 6, lane = t & 63, l15 = lane & 15, q4 = lane >> 4;

#pragma unroll
  for (int i = 0; i < 16; ++i) {
    int p = i * 128 + t;
    int d = p & 63, tok8 = p >> 6;
    u16x8 v;
#pragma unroll
    for (int j = 0; j < 8; ++j) v[j] = Vb[(size_t)(tok8 * 8 + j) * D_MODEL + d];
    *(u16x8*)(vt + d * 264 + tok8 * 8) = v;
  }
  __syncthreads();

  u16* pw = pl + wave * 16 * 264;

  for (int pass = 0; pass < 8; ++pass) {
    const int r0 = pass * 32 + wave * 16;
    const int a = r0 >> 4;              // = 2*pass + wave, wave-uniform

    s16x8 aq[2];
#pragma unroll
    for (int kk = 0; kk < 2; ++kk)
      aq[kk] = *(const s16x8*)(Qb + (size_t)(r0 + l15) * D_MODEL + kk * 32 + q4 * 8);

    f32x4 sc[16];
#pragma unroll
    for (int i = 0; i < 16; ++i) sc[i] = {0.f, 0.f, 0.f, 0.f};

#pragma unroll
    for (int nt = 0; nt < 16; ++nt) {
      if (nt <= a) {
#pragma unroll
        for (int kk = 0; kk < 2; ++kk) {
          s16x8 bk = *(const s16x8*)(Kb + (size_t)(nt * 16 + l15) * D_MODEL + kk * 32 + q4 * 8);
          sc[nt] = __builtin_amdgcn_mfma_f32_16x16x32_bf16(aq[kk], bk, sc[nt], 0, 0, 0);
        }
      }
    }

    float mrow[4] = {-3e38f, -3e38f, -3e38f, -3e38f};
#pragma unroll
    for (int nt = 0; nt < 16; ++nt) {
      if (nt <= a) {
#pragma unroll
        for (int r = 0; r < 4; ++r) {
          int col = nt * 16 + l15;
          int row = r0 + q4 * 4 + r;
          float s = (col > row) ? -1.0e9f : sc[nt][r] * 0.125f;
          sc[nt][r] = s;
          mrow[r] = fmaxf(mrow[r], s);
        }
      }
    }
#pragma unroll
    for (int r = 0; r < 4; ++r)
#pragma unroll
      for (int off = 1; off < 16; off <<= 1)
        mrow[r] = fmaxf(mrow[r], __shfl_xor(mrow[r], off, 64));

    float lrow[4] = {0.f, 0.f, 0.f, 0.f};
#pragma unroll
    for (int nt = 0; nt < 16; ++nt) {
      if (nt <= a) {
#pragma unroll
        for (int r = 0; r < 4; ++r) {
          float e = exp2f((sc[nt][r] - mrow[r]) * 1.44269504f);
          sc[nt][r] = e;
          lrow[r] += e;
        }
      }
    }
#pragma unroll
    for (int r = 0; r < 4; ++r)
#pragma unroll
      for (int off = 1; off < 16; off <<= 1)
        lrow[r] += __shfl_xor(lrow[r], off, 64);

#pragma unroll
    for (int nt = 0; nt < 16; ++nt) {
      if (nt <= a) {
#pragma unroll
        for (int r = 0; r < 4; ++r)
          pw[(q4 * 4 + r) * 264 + nt * 16 + l15] = f2bf(sc[nt][r]);
      }
    }
    if ((a & 1) == 0) {                 // zero partner tile for the K=32 PV step
#pragma unroll
      for (int r = 0; r < 4; ++r)
        pw[(q4 * 4 + r) * 264 + (a + 1) * 16 + l15] = 0;
    }
    const int ktmax = (a + 2) >> 1;

    f32x4 oc[4];
#pragma unroll
    for (int i = 0; i < 4; ++i) oc[i] = {0.f, 0.f, 0.f, 0.f};
#pragma unroll
    for (int kt = 0; kt < 8; ++kt) {
      if (kt < ktmax) {
        s16x8 ap = *(const s16x8*)(pw + l15 * 264 + kt * 32 + q4 * 8);
#pragma unroll
        for (int dt = 0; dt < 4; ++dt) {
          s16x8 bv = *(const s16x8*)(vt + (dt * 16 + l15) * 264 + kt * 32 + q4 * 8);
          oc[dt] = __builtin_amdgcn_mfma_f32_16x16x32_bf16(ap, bv, oc[dt], 0, 0, 0);
        }
      }
    }

    float inv[4];
#pragma unroll
    for (int r = 0; r < 4; ++r) inv[r] = 1.0f / lrow[r];

    // normalize, stage O tile (16 rows x 64 cols) in per-wave LDS, then b128 coalesced stores
#pragma unroll
    for (int dt = 0; dt < 4; ++dt)
#pragma unroll
      for (int r = 0; r < 4; ++r)
        pw[(q4 * 4 + r) * 264 + dt * 16 + l15] = f2bf(oc[dt][r] * inv[r]);
#pragma unroll
    for (int k = 0; k < 2; ++k) {
      int c2 = k * 64 + lane;
      int row = c2 >> 3, c8 = (c2 & 7) * 8;
      u16x8 v = *(const u16x8*)(pw + row * 264 + c8);
      *(u16x8*)(Ob + (size_t)(r0 + row) * D_MODEL + c8) = v;
    }
  }
}

extern "C" void kernel_launch(void* const* d_in, const int* in_sizes, int n_in,
                              void* d_out, int out_size, void* d_ws, size_t ws_size,
                              hipStream_t stream) {
  const float* x  = (const float*)d_in[0];
  const float* Wq = (const float*)d_in[1];
  const float* bq = (const float*)d_in[2];
  const float* Wk = (const float*)d_in[3];
  const float* bk = (const float*)d_in[4];
  const float* Wv = (const float*)d_in[5];
  const float* bv = (const float*)d_in[6];
  const float* Wo = (const float*)d_in[7];
  const float* bo = (const float*)d_in[8];
  float* out = (float*)d_out;

  // ws (bf16 internal): Wt 4x1M, xb 16M, Q/K/V 16M each. O aliases Q. Total 136 MB.
  u16* ws = (u16*)d_ws;
  u16* Wt = ws;
  u16* Xb = ws + (size_t)4 * 1048576;
  u16* Qw = Xb + (size_t)16777216;
  u16* Kw = Qw + (size_t)16777216;
  u16* Vw = Kw + (size_t)16777216;
  u16* Ow = Qw;   // alias

  cast_x<<<dim3(8192), 256, 0, stream>>>(x, Xb);
  transpose_w<<<dim3(16, 16, 4), 256, 0, stream>>>(Wq, Wk, Wv, Wo, Wt);
  // QKV: M=16384, N=3072 -> 64 x 12 = 768 blocks (768 % 8 == 0)
  gemm8<0, 12><<<dim3(768), 512, 0, stream>>>(Xb, Wt, bq, bk, bv, Qw, Kw, Vw);
  attn<<<dim3(64 * 16), 128, 0, stream>>>(Qw, Kw, Vw, Ow);
  // O-proj: M=16384, N=1024 -> 64 x 4 = 256 blocks
  gemm8<1, 4><<<dim3(256), 512, 0, stream>>>(Ow, Wt + (size_t)3 * 1048576, bo,
                                             nullptr, nullptr, out, nullptr, nullptr);
}

// Round 2
// 382.068 us; speedup vs baseline: 1.1748x; 1.1226x over previous
//
#include <hip/hip_runtime.h>
#include <cstdint>
#include <cstddef>

typedef unsigned short u16;
typedef __attribute__((ext_vector_type(8))) short s16x8;      // 8 bf16 = 4 VGPRs (MFMA A/B frag)
typedef __attribute__((ext_vector_type(8))) unsigned short u16x8;
typedef __attribute__((ext_vector_type(4))) float f32x4;      // MFMA C/D frag / float4 load

#define D_MODEL 1024
#define DH 64
#define BS 256
// B*S = 16384 tokens, 64 blocks of 256, 16 heads. External tensors are FLOAT32; internal bf16.

__device__ __forceinline__ u16 f2bf(float f) {
  union { float f; unsigned int i; } x; x.f = f;
  unsigned int r = x.i + 0x7fffu + ((x.i >> 16) & 1u);   // RNE
  return (u16)(r >> 16);
}

__device__ __forceinline__ void gl_lds16(const u16* g, u16* l) {
  __builtin_amdgcn_global_load_lds((const __attribute__((address_space(1))) void*)g,
                                   (__attribute__((address_space(3))) void*)l, 16, 0, 0);
}

__device__ __forceinline__ unsigned lds_off(const u16* p) {
  return (unsigned)(uintptr_t)(const __attribute__((address_space(3))) u16*)p;
}

// ---------------- cast x: f32 -> bf16, 16.7M elems ----------------
__global__ __launch_bounds__(256) void cast_x(const float* __restrict__ x, u16* __restrict__ xb) {
  int i = (blockIdx.x * 256 + threadIdx.x) * 8;
  f32x4 a0 = *(const f32x4*)(x + i);
  f32x4 a1 = *(const f32x4*)(x + i + 4);
  u16x8 v;
#pragma unroll
  for (int j = 0; j < 4; ++j) { v[j] = f2bf(a0[j]); v[j + 4] = f2bf(a1[j]); }
  *(u16x8*)(xb + i) = v;
}

// ---------------- W transpose+cast: Wt[n][k] = bf16(W[k][n]) (1024x1024 f32 -> bf16, x4) ----------------
__global__ __launch_bounds__(256) void transpose_w(const float* __restrict__ w0,
                                                   const float* __restrict__ w1,
                                                   const float* __restrict__ w2,
                                                   const float* __restrict__ w3,
                                                   u16* __restrict__ out) {
  __shared__ u16 tile[64][65];
  const int z = blockIdx.z;
  const float* W = (z == 0) ? w0 : (z == 1) ? w1 : (z == 2) ? w2 : w3;
  u16* O = out + (size_t)z * (D_MODEL * D_MODEL);
  const int kb = blockIdx.y * 64, nb = blockIdx.x * 64;
  const int t = threadIdx.x;
#pragma unroll
  for (int i = 0; i < 16; ++i) {
    int e = i * 256 + t;
    int r = e >> 6, c = e & 63;
    tile[r][c] = f2bf(W[(size_t)(kb + r) * D_MODEL + nb + c]);
  }
  __syncthreads();
#pragma unroll
  for (int i = 0; i < 16; ++i) {
    int e = i * 256 + t;
    int r = e >> 6, c = e & 63;
    O[(size_t)(nb + r) * D_MODEL + kb + c] = tile[c][r];
  }
}

// ================= 256x256 8-phase GEMM (m201 template, plain HIP + asm ds_read) =================
// BM=BN=256, BK=64, 512 threads = 8 waves (2M x 4N), per-wave C = 128x64.
// LDS 128 KiB: As[2][256][64], Bs[2][256][64] bf16, double-buffered.
// st_16x32 swizzle: byte ^= ((row>>2)&1)<<5. Linear gl_lds DEST + inverse-swizzled global
// SOURCE + swizzled ds_read address (both-sides rule).
// T4 (counted vmcnt) requires the LDS reads be INVISIBLE to hipcc's alias analysis —
// otherwise it inserts its own vmcnt drains before every ds_read (R1 post-mortem: MfmaUtil 28%).
// Hence inline-asm ds_read_b128 + explicit lgkmcnt(0) + sched_barrier(0) (rule #18).

#define TIU 16384   // u16 per 256x64 buffer
#define HIU 8192    // u16 per 128x64 half-tile

__device__ __forceinline__ void stage_half(const u16* __restrict__ src, int rowG0, int k0,
                                           u16* ldst, int tid) {
#pragma unroll
  for (int i = 0; i < 2; ++i) {
    int c = i * 512 + tid;                       // linear 16B chunk in half-tile
    int cs = c ^ (((c >> 5) & 1) << 1);          // inverse st_16x32 swizzle (involution)
    gl_lds16(src + (size_t)(rowG0 + (cs >> 3)) * D_MODEL + k0 + (cs & 7) * 8,
             ldst + c * 8);
  }
}

#define NOPX ((void)0)
#define BARX() __builtin_amdgcn_s_barrier()
#define VMW(N) asm volatile("s_waitcnt vmcnt(" #N ")" ::: "memory")
#define SBAR() __builtin_amdgcn_sched_barrier(0)

// asm ds_read_b128: base VGPR (byte addr in LDS) + literal offset
#define DSR128(dst, b, off) asm volatile("ds_read_b128 %0, %1 offset:" #off : "=v"(dst) : "v"(b))

// A frags for half MH: rows arow + MH*64 + mt*16, cols kk*32 + qx (u16), row stride 128 B
#define LDA8(P, MH) do { \
  const unsigned _b = ((P) ? aB1 : aB0) + (MH) * 8192u; \
  DSR128(a[0][0], _b, 0);    DSR128(a[0][1], _b, 64); \
  DSR128(a[1][0], _b, 2048); DSR128(a[1][1], _b, 2112); \
  DSR128(a[2][0], _b, 4096); DSR128(a[2][1], _b, 4160); \
  DSR128(a[3][0], _b, 6144); DSR128(a[3][1], _b, 6208); \
} while (0)

#define LDB4(P, NH) do { \
  const unsigned _b = ((P) ? bB1 : bB0) + (NH) * 4096u; \
  DSR128(b[NH][0][0], _b, 0);    DSR128(b[NH][0][1], _b, 64); \
  DSR128(b[NH][1][0], _b, 2048); DSR128(b[NH][1][1], _b, 2112); \
} while (0)

#define MF16(MH, NH) do { \
  __builtin_amdgcn_s_setprio(1); \
  _Pragma("unroll") for (int kk = 0; kk < 2; ++kk) \
  _Pragma("unroll") for (int mt = 0; mt < 4; ++mt) \
  _Pragma("unroll") for (int nt = 0; nt < 2; ++nt) \
    acc[(MH) * 4 + mt][(NH) * 2 + nt] = __builtin_amdgcn_mfma_f32_16x16x32_bf16( \
        a[mt][kk], b[NH][nt][kk], acc[(MH) * 4 + mt][(NH) * 2 + nt], 0, 0, 0); \
  __builtin_amdgcn_s_setprio(0); \
} while (0)

#define STA(T, H) stage_half(A, rowBase + (H) * 128, (T) * 64, As + ((T) & 1) * TIU + (H) * HIU, t)
#define STB(T, H) stage_half(W, colBase + (H) * 128, (T) * 64, Bs + ((T) & 1) * TIU + (H) * HIU, t)

// barrier -> drain LDS reads -> pin scheduler -> MFMA
#define PWAIT() do { BARX(); asm volatile("s_waitcnt lgkmcnt(0)"); SBAR(); } while (0)

// One K-tile = 4 phases; quadrant order (0,0),(0,1),(1,1),(1,0): B halves reload once, A once.
#define KTILE(P, S1, S2, S3, S4, WAIT) do { \
  LDA8(P, 0); LDB4(P, 0); S1; PWAIT();            MF16(0, 0); BARX(); \
  LDB4(P, 1);             S2; PWAIT();            MF16(0, 1); BARX(); \
  LDA8(P, 1);             S3; PWAIT();            MF16(1, 1); BARX(); \
                    S4; WAIT; BARX(); SBAR();     MF16(1, 0); BARX(); \
} while (0)

// MODE 0: fused QKV (bf16 out, 3 planes, N=3072). MODE 1: O-proj (f32 out, N=1024).
template <int MODE, int NCB>
__global__ __launch_bounds__(512, 2) void gemm8(
    const u16* __restrict__ A, const u16* __restrict__ W,
    const float* __restrict__ b0, const float* __restrict__ b1, const float* __restrict__ b2,
    void* __restrict__ o0, void* __restrict__ o1, void* __restrict__ o2) {
  __shared__ u16 As[2 * TIU];
  __shared__ u16 Bs[2 * TIU];

  // bijective XCD swizzle (nwg % 8 == 0 by construction: 768 / 256)
  const int nwg = gridDim.x;
  const int wg = blockIdx.x;
  const int swz = (wg & 7) * (nwg >> 3) + (wg >> 3);
  const int rowBase = (swz / NCB) * 256;
  const int colBase = (swz % NCB) * 256;

  const int t = threadIdx.x;
  const int wave = t >> 6, lane = t & 63, l15 = lane & 15, q4 = lane >> 4;
  const int wm = wave >> 2, wn = wave & 3;
  const int qx = (q4 * 8) ^ ((lane & 4) << 2);   // read-side st_16x32 swizzle folded into col
  const int arow = wm * 128 + l15;
  const int brow = wn * 64 + l15;

  // LDS byte bases for asm ds_read (buffer 0 / buffer 1)
  const unsigned aB0 = lds_off(As) + (unsigned)arow * 128u + (unsigned)qx * 2u;
  const unsigned aB1 = aB0 + 32768u;
  const unsigned bB0 = lds_off(Bs) + (unsigned)brow * 128u + (unsigned)qx * 2u;
  const unsigned bB1 = bB0 + 32768u;

  f32x4 acc[8][4];
#pragma unroll
  for (int i = 0; i < 8; ++i)
#pragma unroll
    for (int j = 0; j < 4; ++j) acc[i][j] = {0.f, 0.f, 0.f, 0.f};

  s16x8 a[4][2];        // A frags: 4 m-tiles x 2 kk for current half
  s16x8 b[2][2][2];     // B frags: [nh][nt][kk], both halves live

  // Prologue: tile0 fully + 3 half-tiles of tile1 (issue order B0,B1,A0,A1 | B0,B1,A0)
  STB(0, 0); STB(0, 1); STA(0, 0); STA(0, 1);
  VMW(4);
  STB(1, 0); STB(1, 1); STA(1, 0);
  VMW(6);
  BARX();

#pragma unroll 1
  for (int tg = 0; tg < 14; tg += 2) {
    KTILE(0, STA(tg + 1, 1), STB(tg + 2, 0), STB(tg + 2, 1), STA(tg + 2, 0), VMW(6));
    KTILE(1, STA(tg + 2, 1), STB(tg + 3, 0), STB(tg + 3, 1), STA(tg + 3, 0), VMW(6));
  }
  // Tail: tile 14 finishes tile15's staging then drains; tile 15 computes only.
  KTILE(0, STA(15, 1), NOPX, NOPX, NOPX, VMW(0));
  KTILE(1, NOPX, NOPX, NOPX, NOPX, NOPX);

  // Epilogue: C/D map col = l15, row = q4*4 + r. ni INNERMOST so each row's 128B
  // line (64 cols x 2B) is written back-to-back -> no partial-line HBM double-write.
  if constexpr (MODE == 0) {
    const int z = colBase >> 10;                 // whole block is one z-plane (256 | 1024)
    const float* bias = (z == 0) ? b0 : (z == 1) ? b1 : b2;
    u16* Out = (u16*)((z == 0) ? o0 : (z == 1) ? o1 : o2);
    const int colL = (colBase & 1023) + wn * 64;
    float bv[4];
#pragma unroll
    for (int ni = 0; ni < 4; ++ni) bv[ni] = bias[colL + ni * 16 + l15];
#pragma unroll
    for (int mi = 0; mi < 8; ++mi) {
#pragma unroll
      for (int r = 0; r < 4; ++r) {
        size_t row = (size_t)(rowBase + wm * 128 + mi * 16 + q4 * 4 + r);
#pragma unroll
        for (int ni = 0; ni < 4; ++ni)
          Out[row * D_MODEL + colL + ni * 16 + l15] = f2bf(acc[mi][ni][r] + bv[ni]);
      }
    }
  } else {
    float* Out = (float*)o0;
    const int colL = colBase + wn * 64;
    float bv[4];
#pragma unroll
    for (int ni = 0; ni < 4; ++ni) bv[ni] = b0[colL + ni * 16 + l15];
#pragma unroll
    for (int mi = 0; mi < 8; ++mi) {
#pragma unroll
      for (int r = 0; r < 4; ++r) {
        size_t row = (size_t)(rowBase + wm * 128 + mi * 16 + q4 * 4 + r);
#pragma unroll
        for (int ni = 0; ni < 4; ++ni)
          Out[row * D_MODEL + colL + ni * 16 + l15] = acc[mi][ni][r] + bv[ni];
      }
    }
  }
}

// ---------------- Attention: one WG (128 thr = 2 waves) per (block n, head h) ----------------
// All causal-skip conditions are wave-uniform guards inside constant-trip unrolled loops
// (NO dynamic break: a break defeats unrolling and forces sc[] into scratch — R4 lesson).
__global__ __launch_bounds__(128) void attn(const u16* __restrict__ Q, const u16* __restrict__ K,
                                            const u16* __restrict__ V, u16* __restrict__ O) {
  __shared__ u16 vt[64 * 264];        // V^T: [d][tok], row stride 264
  __shared__ u16 pl[2 * 16 * 264];    // per-wave P / O staging: [wave][16 rows][256(+pad) cols]
  const int g = blockIdx.x;
  const int n = g >> 4, h = g & 15;
  const size_t base = (size_t)n * BS * D_MODEL + (size_t)h * DH;
  const u16* Qb = Q + base;
  const u16* Kb = K + base;
  const u16* Vb = V + base;
  u16* Ob = O + base;
  const int t = threadIdx.x, wave = t >> 6, lane = t & 63, l15 = lane & 15, q4 = lane >> 4;

#pragma unroll
  for (int i = 0; i < 16; ++i) {
    int p = i * 128 + t;
    int d = p & 63, tok8 = p >> 6;
    u16x8 v;
#pragma unroll
    for (int j = 0; j < 8; ++j) v[j] = Vb[(size_t)(tok8 * 8 + j) * D_MODEL + d];
    *(u16x8*)(vt + d * 264 + tok8 * 8) = v;
  }
  __syncthreads();

  u16* pw = pl + wave * 16 * 264;

  for (int pass = 0; pass < 8; ++pass) {
    const int r0 = pass * 32 + wave * 16;
    const int a = r0 >> 4;              // = 2*pass + wave, wave-uniform

    s16x8 aq[2];
#pragma unroll
    for (int kk = 0; kk < 2; ++kk)
      aq[kk] = *(const s16x8*)(Qb + (size_t)(r0 + l15) * D_MODEL + kk * 32 + q4 * 8);

    f32x4 sc[16];
#pragma unroll
    for (int i = 0; i < 16; ++i) sc[i] = {0.f, 0.f, 0.f, 0.f};

#pragma unroll
    for (int nt = 0; nt < 16; ++nt) {
      if (nt <= a) {
#pragma unroll
        for (int kk = 0; kk < 2; ++kk) {
          s16x8 bk = *(const s16x8*)(Kb + (size_t)(nt * 16 + l15) * D_MODEL + kk * 32 + q4 * 8);
          sc[nt] = __builtin_amdgcn_mfma_f32_16x16x32_bf16(aq[kk], bk, sc[nt], 0, 0, 0);
        }
      }
    }

    float mrow[4] = {-3e38f, -3e38f, -3e38f, -3e38f};
#pragma unroll
    for (int nt = 0; nt < 16; ++nt) {
      if (nt <= a) {
#pragma unroll
        for (int r = 0; r < 4; ++r) {
          int col = nt * 16 + l15;
          int row = r0 + q4 * 4 + r;
          float s = (col > row) ? -1.0e9f : sc[nt][r] * 0.125f;
          sc[nt][r] = s;
          mrow[r] = fmaxf(mrow[r], s);
        }
      }
    }
#pragma unroll
    for (int r = 0; r < 4; ++r)
#pragma unroll
      for (int off = 1; off < 16; off <<= 1)
        mrow[r] = fmaxf(mrow[r], __shfl_xor(mrow[r], off, 64));

    float lrow[4] = {0.f, 0.f, 0.f, 0.f};
#pragma unroll
    for (int nt = 0; nt < 16; ++nt) {
      if (nt <= a) {
#pragma unroll
        for (int r = 0; r < 4; ++r) {
          float e = exp2f((sc[nt][r] - mrow[r]) * 1.44269504f);
          sc[nt][r] = e;
          lrow[r] += e;
        }
      }
    }
#pragma unroll
    for (int r = 0; r < 4; ++r)
#pragma unroll
      for (int off = 1; off < 16; off <<= 1)
        lrow[r] += __shfl_xor(lrow[r], off, 64);

#pragma unroll
    for (int nt = 0; nt < 16; ++nt) {
      if (nt <= a) {
#pragma unroll
        for (int r = 0; r < 4; ++r)
          pw[(q4 * 4 + r) * 264 + nt * 16 + l15] = f2bf(sc[nt][r]);
      }
    }
    if ((a & 1) == 0) {                 // zero partner tile for the K=32 PV step
#pragma unroll
      for (int r = 0; r < 4; ++r)
        pw[(q4 * 4 + r) * 264 + (a + 1) * 16 + l15] = 0;
    }
    const int ktmax = (a + 2) >> 1;

    f32x4 oc[4];
#pragma unroll
    for (int i = 0; i < 4; ++i) oc[i] = {0.f, 0.f, 0.f, 0.f};
#pragma unroll
    for (int kt = 0; kt < 8; ++kt) {
      if (kt < ktmax) {
        s16x8 ap = *(const s16x8*)(pw + l15 * 264 + kt * 32 + q4 * 8);
#pragma unroll
        for (int dt = 0; dt < 4; ++dt) {
          s16x8 bv = *(const s16x8*)(vt + (dt * 16 + l15) * 264 + kt * 32 + q4 * 8);
          oc[dt] = __builtin_amdgcn_mfma_f32_16x16x32_bf16(ap, bv, oc[dt], 0, 0, 0);
        }
      }
    }

    float inv[4];
#pragma unroll
    for (int r = 0; r < 4; ++r) inv[r] = 1.0f / lrow[r];

    // normalize, stage O tile (16 rows x 64 cols) in per-wave LDS, then b128 coalesced stores
#pragma unroll
    for (int dt = 0; dt < 4; ++dt)
#pragma unroll
      for (int r = 0; r < 4; ++r)
        pw[(q4 * 4 + r) * 264 + dt * 16 + l15] = f2bf(oc[dt][r] * inv[r]);
#pragma unroll
    for (int k = 0; k < 2; ++k) {
      int c2 = k * 64 + lane;
      int row = c2 >> 3, c8 = (c2 & 7) * 8;
      u16x8 v = *(const u16x8*)(pw + row * 264 + c8);
      *(u16x8*)(Ob + (size_t)(r0 + row) * D_MODEL + c8) = v;
    }
  }
}

extern "C" void kernel_launch(void* const* d_in, const int* in_sizes, int n_in,
                              void* d_out, int out_size, void* d_ws, size_t ws_size,
                              hipStream_t stream) {
  const float* x  = (const float*)d_in[0];
  const float* Wq = (const float*)d_in[1];
  const float* bq = (const float*)d_in[2];
  const float* Wk = (const float*)d_in[3];
  const float* bk = (const float*)d_in[4];
  const float* Wv = (const float*)d_in[5];
  const float* bv = (const float*)d_in[6];
  const float* Wo = (const float*)d_in[7];
  const float* bo = (const float*)d_in[8];
  float* out = (float*)d_out;

  // ws (bf16 internal): Wt 4x1M, xb 16M, Q/K/V 16M each. O aliases Q. Total 136 MB.
  u16* ws = (u16*)d_ws;
  u16* Wt = ws;
  u16* Xb = ws + (size_t)4 * 1048576;
  u16* Qw = Xb + (size_t)16777216;
  u16* Kw = Qw + (size_t)16777216;
  u16* Vw = Kw + (size_t)16777216;
  u16* Ow = Qw;   // alias

  cast_x<<<dim3(8192), 256, 0, stream>>>(x, Xb);
  transpose_w<<<dim3(16, 16, 4), 256, 0, stream>>>(Wq, Wk, Wv, Wo, Wt);
  // QKV: M=16384, N=3072 -> 64 x 12 = 768 blocks (768 % 8 == 0)
  gemm8<0, 12><<<dim3(768), 512, 0, stream>>>(Xb, Wt, bq, bk, bv, Qw, Kw, Vw);
  attn<<<dim3(64 * 16), 128, 0, stream>>>(Qw, Kw, Vw, Ow);
  // O-proj: M=16384, N=1024 -> 64 x 4 = 256 blocks
  gemm8<1, 4><<<dim3(256), 512, 0, stream>>>(Ow, Wt + (size_t)3 * 1048576, bo,
                                             nullptr, nullptr, out, nullptr, nullptr);
}

// Round 3
// 370.971 us; speedup vs baseline: 1.2099x; 1.0299x over previous
//
#include <hip/hip_runtime.h>
#include <cstdint>
#include <cstddef>

typedef unsigned short u16;
typedef __attribute__((ext_vector_type(8))) short s16x8;      // 8 bf16 = 4 VGPRs (MFMA A/B frag)
typedef __attribute__((ext_vector_type(8))) unsigned short u16x8;
typedef __attribute__((ext_vector_type(4))) float f32x4;      // MFMA C/D frag / float4 load

#define D_MODEL 1024
#define DH 64
#define BS 256
// B*S = 16384 tokens, 64 blocks of 256, 16 heads. External tensors are FLOAT32; internal bf16.

__device__ __forceinline__ u16 f2bf(float f) {
  union { float f; unsigned int i; } x; x.f = f;
  unsigned int r = x.i + 0x7fffu + ((x.i >> 16) & 1u);   // RNE
  return (u16)(r >> 16);
}

__device__ __forceinline__ void gl_lds16(const u16* g, u16* l) {
  __builtin_amdgcn_global_load_lds((const __attribute__((address_space(1))) void*)g,
                                   (__attribute__((address_space(3))) void*)l, 16, 0, 0);
}

__device__ __forceinline__ unsigned lds_off(const u16* p) {
  return (unsigned)(uintptr_t)(const __attribute__((address_space(3))) u16*)p;
}

// ---------------- cast x: f32 -> bf16, 16.7M elems ----------------
__global__ __launch_bounds__(256) void cast_x(const float* __restrict__ x, u16* __restrict__ xb) {
  int i = (blockIdx.x * 256 + threadIdx.x) * 8;
  f32x4 a0 = *(const f32x4*)(x + i);
  f32x4 a1 = *(const f32x4*)(x + i + 4);
  u16x8 v;
#pragma unroll
  for (int j = 0; j < 4; ++j) { v[j] = f2bf(a0[j]); v[j + 4] = f2bf(a1[j]); }
  *(u16x8*)(xb + i) = v;
}

// ---------------- W transpose+cast: Wt[n][k] = bf16(W[k][n]) (1024x1024 f32 -> bf16, x4) ----------------
__global__ __launch_bounds__(256) void transpose_w(const float* __restrict__ w0,
                                                   const float* __restrict__ w1,
                                                   const float* __restrict__ w2,
                                                   const float* __restrict__ w3,
                                                   u16* __restrict__ out) {
  __shared__ u16 tile[64][65];
  const int z = blockIdx.z;
  const float* W = (z == 0) ? w0 : (z == 1) ? w1 : (z == 2) ? w2 : w3;
  u16* O = out + (size_t)z * (D_MODEL * D_MODEL);
  const int kb = blockIdx.y * 64, nb = blockIdx.x * 64;
  const int t = threadIdx.x;
#pragma unroll
  for (int i = 0; i < 16; ++i) {
    int e = i * 256 + t;
    int r = e >> 6, c = e & 63;
    tile[r][c] = f2bf(W[(size_t)(kb + r) * D_MODEL + nb + c]);
  }
  __syncthreads();
#pragma unroll
  for (int i = 0; i < 16; ++i) {
    int e = i * 256 + t;
    int r = e >> 6, c = e & 63;
    O[(size_t)(nb + r) * D_MODEL + kb + c] = tile[c][r];
  }
}

// ================= 256x256 8-phase GEMM (m201 template, plain HIP + asm ds_read) =================
// BM=BN=256, BK=64, 512 threads = 8 waves (2M x 4N), per-wave C = 128x64.
// LDS 128 KiB: As[2][256][64], Bs[2][256][64] bf16, double-buffered.
// T2 swizzle (FULL, R2 fix): byte ^= ((row&7)<<4) — 16 aliasing rows spread over all 8
// 16B slots of a 128B row (2 rows/slot = 2-way = free, m136). Applied both-sides (rule #21):
// linear gl_lds DEST + inverse-permuted global SOURCE chunk (c ^ ((c>>3)&7)) + swizzled
// ds_read column ((q4 ^ (l15&7))<<4), with separate kk=0/kk=1 bases (XOR of bit 6 is not
// expressible as a literal ds offset).
// T4 (counted vmcnt) requires the LDS reads be INVISIBLE to hipcc's alias analysis —
// hence inline-asm ds_read_b128 + explicit lgkmcnt(0) + sched_barrier(0) (rule #18).

#define TIU 16384   // u16 per 256x64 buffer
#define HIU 8192    // u16 per 128x64 half-tile

__device__ __forceinline__ void stage_half(const u16* __restrict__ src, int rowG0, int k0,
                                           u16* ldst, int tid) {
#pragma unroll
  for (int i = 0; i < 2; ++i) {
    int c = i * 512 + tid;                       // linear 16B chunk in half-tile
    int cs = c ^ ((c >> 3) & 7);                 // inverse (row&7)<<4 swizzle (involution)
    gl_lds16(src + (size_t)(rowG0 + (cs >> 3)) * D_MODEL + k0 + (cs & 7) * 8,
             ldst + c * 8);
  }
}

#define NOPX ((void)0)
#define BARX() __builtin_amdgcn_s_barrier()
#define VMW(N) asm volatile("s_waitcnt vmcnt(" #N ")" ::: "memory")
#define SBAR() __builtin_amdgcn_sched_barrier(0)
#define LGK8() asm volatile("s_waitcnt lgkmcnt(8)")

// asm ds_read_b128: base VGPR (byte addr in LDS) + literal offset
#define DSR128(dst, b, off) asm volatile("ds_read_b128 %0, %1 offset:" #off : "=v"(dst) : "v"(b))

// A frags for half MH: rows arow + MH*64 + mt*16 (row&7 == l15&7, invariant under offsets).
// kk=0 via aK0 base, kk=1 via aK1 = aK0 ^ 64. Row steps (mt*16 rows = 2048 B) are literals.
#define LDA8(P, MH) do { \
  const unsigned _o = (P) * 32768u + (MH) * 8192u; \
  DSR128(a[0][0], aK0 + _o, 0);    DSR128(a[0][1], aK1 + _o, 0); \
  DSR128(a[1][0], aK0 + _o, 2048); DSR128(a[1][1], aK1 + _o, 2048); \
  DSR128(a[2][0], aK0 + _o, 4096); DSR128(a[2][1], aK1 + _o, 4096); \
  DSR128(a[3][0], aK0 + _o, 6144); DSR128(a[3][1], aK1 + _o, 6144); \
} while (0)

#define LDB4(P, NH) do { \
  const unsigned _o = (P) * 32768u + (NH) * 4096u; \
  DSR128(b[NH][0][0], bK0 + _o, 0);    DSR128(b[NH][0][1], bK1 + _o, 0); \
  DSR128(b[NH][1][0], bK0 + _o, 2048); DSR128(b[NH][1][1], bK1 + _o, 2048); \
} while (0)

#define MF16(MH, NH) do { \
  __builtin_amdgcn_s_setprio(1); \
  _Pragma("unroll") for (int kk = 0; kk < 2; ++kk) \
  _Pragma("unroll") for (int mt = 0; mt < 4; ++mt) \
  _Pragma("unroll") for (int nt = 0; nt < 2; ++nt) \
    acc[(MH) * 4 + mt][(NH) * 2 + nt] = __builtin_amdgcn_mfma_f32_16x16x32_bf16( \
        a[mt][kk], b[NH][nt][kk], acc[(MH) * 4 + mt][(NH) * 2 + nt], 0, 0, 0); \
  __builtin_amdgcn_s_setprio(0); \
} while (0)

#define STA(T, H) stage_half(A, rowBase + (H) * 128, (T) * 64, As + ((T) & 1) * TIU + (H) * HIU, t)
#define STB(T, H) stage_half(W, colBase + (H) * 128, (T) * 64, Bs + ((T) & 1) * TIU + (H) * HIU, t)

// barrier -> drain LDS reads -> pin scheduler -> MFMA
#define PWAIT() do { BARX(); asm volatile("s_waitcnt lgkmcnt(0)"); SBAR(); } while (0)

// One K-tile = 4 phases; quadrant order (0,0),(0,1),(1,1),(1,0): B halves reload once, A once.
// Phase 1 issues 12 ds_reads -> lgkmcnt(8) pacing before the barrier (m201 optional clause).
#define KTILE(P, S1, S2, S3, S4, WAIT) do { \
  LDA8(P, 0); LDB4(P, 0); S1; LGK8(); PWAIT();  MF16(0, 0); BARX(); \
  LDB4(P, 1);             S2; PWAIT();          MF16(0, 1); BARX(); \
  LDA8(P, 1);             S3; PWAIT();          MF16(1, 1); BARX(); \
                    S4; WAIT; BARX(); SBAR();   MF16(1, 0); BARX(); \
} while (0)

// MODE 0: fused QKV (bf16 out, 3 planes, N=3072). MODE 1: O-proj (f32 out, N=1024).
template <int MODE, int NCB>
__global__ __launch_bounds__(512, 2) void gemm8(
    const u16* __restrict__ A, const u16* __restrict__ W,
    const float* __restrict__ b0, const float* __restrict__ b1, const float* __restrict__ b2,
    void* __restrict__ o0, void* __restrict__ o1, void* __restrict__ o2) {
  __shared__ u16 As[2 * TIU];
  __shared__ u16 Bs[2 * TIU];

  // bijective XCD swizzle (nwg % 8 == 0 by construction: 768 / 256)
  const int nwg = gridDim.x;
  const int wg = blockIdx.x;
  const int swz = (wg & 7) * (nwg >> 3) + (wg >> 3);
  const int rowBase = (swz / NCB) * 256;
  const int colBase = (swz % NCB) * 256;

  const int t = threadIdx.x;
  const int wave = t >> 6, lane = t & 63, l15 = lane & 15, q4 = lane >> 4;
  const int wm = wave >> 2, wn = wave & 3;
  const int arow = wm * 128 + l15;
  const int brow = wn * 64 + l15;

  // LDS byte bases for asm ds_read (kk=0 / kk=1), swizzled column = (q4 ^ (l15&7)) << 4
  const unsigned swzc = (unsigned)((q4 ^ (l15 & 7)) << 4);
  const unsigned aK0 = lds_off(As) + (unsigned)arow * 128u + swzc;
  const unsigned aK1 = aK0 ^ 64u;
  const unsigned bK0 = lds_off(Bs) + (unsigned)brow * 128u + swzc;
  const unsigned bK1 = bK0 ^ 64u;

  f32x4 acc[8][4];
#pragma unroll
  for (int i = 0; i < 8; ++i)
#pragma unroll
    for (int j = 0; j < 4; ++j) acc[i][j] = {0.f, 0.f, 0.f, 0.f};

  s16x8 a[4][2];        // A frags: 4 m-tiles x 2 kk for current half
  s16x8 b[2][2][2];     // B frags: [nh][nt][kk], both halves live

  // Prologue: tile0 fully + 3 half-tiles of tile1 (issue order B0,B1,A0,A1 | B0,B1,A0)
  STB(0, 0); STB(0, 1); STA(0, 0); STA(0, 1);
  VMW(4);
  STB(1, 0); STB(1, 1); STA(1, 0);
  VMW(6);
  BARX();

#pragma unroll 1
  for (int tg = 0; tg < 14; tg += 2) {
    KTILE(0, STA(tg + 1, 1), STB(tg + 2, 0), STB(tg + 2, 1), STA(tg + 2, 0), VMW(6));
    KTILE(1, STA(tg + 2, 1), STB(tg + 3, 0), STB(tg + 3, 1), STA(tg + 3, 0), VMW(6));
  }
  // Tail: tile 14 finishes tile15's staging then drains; tile 15 computes only.
  KTILE(0, STA(15, 1), NOPX, NOPX, NOPX, VMW(0));
  KTILE(1, NOPX, NOPX, NOPX, NOPX, NOPX);

  // Epilogue: C/D map col = l15, row = q4*4 + r. ni INNERMOST so each row's 128B
  // line (64 cols x 2B) is written back-to-back -> no partial-line HBM double-write.
  if constexpr (MODE == 0) {
    const int z = colBase >> 10;                 // whole block is one z-plane (256 | 1024)
    const float* bias = (z == 0) ? b0 : (z == 1) ? b1 : b2;
    u16* Out = (u16*)((z == 0) ? o0 : (z == 1) ? o1 : o2);
    const int colL = (colBase & 1023) + wn * 64;
    float bv[4];
#pragma unroll
    for (int ni = 0; ni < 4; ++ni) bv[ni] = bias[colL + ni * 16 + l15];
#pragma unroll
    for (int mi = 0; mi < 8; ++mi) {
#pragma unroll
      for (int r = 0; r < 4; ++r) {
        size_t row = (size_t)(rowBase + wm * 128 + mi * 16 + q4 * 4 + r);
#pragma unroll
        for (int ni = 0; ni < 4; ++ni)
          Out[row * D_MODEL + colL + ni * 16 + l15] = f2bf(acc[mi][ni][r] + bv[ni]);
      }
    }
  } else {
    float* Out = (float*)o0;
    const int colL = colBase + wn * 64;
    float bv[4];
#pragma unroll
    for (int ni = 0; ni < 4; ++ni) bv[ni] = b0[colL + ni * 16 + l15];
#pragma unroll
    for (int mi = 0; mi < 8; ++mi) {
#pragma unroll
      for (int r = 0; r < 4; ++r) {
        size_t row = (size_t)(rowBase + wm * 128 + mi * 16 + q4 * 4 + r);
#pragma unroll
        for (int ni = 0; ni < 4; ++ni)
          Out[row * D_MODEL + colL + ni * 16 + l15] = acc[mi][ni][r] + bv[ni];
      }
    }
  }
}

// ---------------- Attention: one WG (128 thr = 2 waves) per (block n, head h) ----------------
// All causal-skip conditions are wave-uniform guards inside constant-trip unrolled loops
// (NO dynamic break: a break defeats unrolling and forces sc[] into scratch — R4 lesson).
__global__ __launch_bounds__(128) void attn(const u16* __restrict__ Q, const u16* __restrict__ K,
                                            const u16* __restrict__ V, u16* __restrict__ O) {
  __shared__ u16 vt[64 * 264];        // V^T: [d][tok], row stride 264
  __shared__ u16 pl[2 * 16 * 264];    // per-wave P / O staging: [wave][16 rows][256(+pad) cols]
  const int g = blockIdx.x;
  const int n = g >> 4, h = g & 15;
  const size_t base = (size_t)n * BS * D_MODEL + (size_t)h * DH;
  const u16* Qb = Q + base;
  const u16* Kb = K + base;
  const u16* Vb = V + base;
  u16* Ob = O + base;
  const int t = threadIdx.x, wave = t >> 6, lane = t & 63, l15 = lane & 15, q4 = lane >> 4;

#pragma unroll
  for (int i = 0; i < 16; ++i) {
    int p = i * 128 + t;
    int d = p & 63, tok8 = p >> 6;
    u16x8 v;
#pragma unroll
    for (int j = 0; j < 8; ++j) v[j] = Vb[(size_t)(tok8 * 8 + j) * D_MODEL + d];
    *(u16x8*)(vt + d * 264 + tok8 * 8) = v;
  }
  __syncthreads();

  u16* pw = pl + wave * 16 * 264;

  for (int pass = 0; pass < 8; ++pass) {
    const int r0 = pass * 32 + wave * 16;
    const int a = r0 >> 4;              // = 2*pass + wave, wave-uniform

    s16x8 aq[2];
#pragma unroll
    for (int kk = 0; kk < 2; ++kk)
      aq[kk] = *(const s16x8*)(Qb + (size_t)(r0 + l15) * D_MODEL + kk * 32 + q4 * 8);

    f32x4 sc[16];
#pragma unroll
    for (int i = 0; i < 16; ++i) sc[i] = {0.f, 0.f, 0.f, 0.f};

    __builtin_amdgcn_s_setprio(1);      // T5: favor this wave's QK^T MFMA burst
#pragma unroll
    for (int nt = 0; nt < 16; ++nt) {
      if (nt <= a) {
#pragma unroll
        for (int kk = 0; kk < 2; ++kk) {
          s16x8 bk = *(const s16x8*)(Kb + (size_t)(nt * 16 + l15) * D_MODEL + kk * 32 + q4 * 8);
          sc[nt] = __builtin_amdgcn_mfma_f32_16x16x32_bf16(aq[kk], bk, sc[nt], 0, 0, 0);
        }
      }
    }
    __builtin_amdgcn_s_setprio(0);

    float mrow[4] = {-3e38f, -3e38f, -3e38f, -3e38f};
#pragma unroll
    for (int nt = 0; nt < 16; ++nt) {
      if (nt <= a) {
#pragma unroll
        for (int r = 0; r < 4; ++r) {
          int col = nt * 16 + l15;
          int row = r0 + q4 * 4 + r;
          float s = (col > row) ? -1.0e9f : sc[nt][r] * 0.125f;
          sc[nt][r] = s;
          mrow[r] = fmaxf(mrow[r], s);
        }
      }
    }
#pragma unroll
    for (int r = 0; r < 4; ++r)
#pragma unroll
      for (int off = 1; off < 16; off <<= 1)
        mrow[r] = fmaxf(mrow[r], __shfl_xor(mrow[r], off, 64));

    float lrow[4] = {0.f, 0.f, 0.f, 0.f};
#pragma unroll
    for (int nt = 0; nt < 16; ++nt) {
      if (nt <= a) {
#pragma unroll
        for (int r = 0; r < 4; ++r) {
          float e = exp2f((sc[nt][r] - mrow[r]) * 1.44269504f);
          sc[nt][r] = e;
          lrow[r] += e;
        }
      }
    }
#pragma unroll
    for (int r = 0; r < 4; ++r)
#pragma unroll
      for (int off = 1; off < 16; off <<= 1)
        lrow[r] += __shfl_xor(lrow[r], off, 64);

#pragma unroll
    for (int nt = 0; nt < 16; ++nt) {
      if (nt <= a) {
#pragma unroll
        for (int r = 0; r < 4; ++r)
          pw[(q4 * 4 + r) * 264 + nt * 16 + l15] = f2bf(sc[nt][r]);
      }
    }
    if ((a & 1) == 0) {                 // zero partner tile for the K=32 PV step
#pragma unroll
      for (int r = 0; r < 4; ++r)
        pw[(q4 * 4 + r) * 264 + (a + 1) * 16 + l15] = 0;
    }
    const int ktmax = (a + 2) >> 1;

    f32x4 oc[4];
#pragma unroll
    for (int i = 0; i < 4; ++i) oc[i] = {0.f, 0.f, 0.f, 0.f};
    __builtin_amdgcn_s_setprio(1);      // T5: favor this wave's PV MFMA burst
#pragma unroll
    for (int kt = 0; kt < 8; ++kt) {
      if (kt < ktmax) {
        s16x8 ap = *(const s16x8*)(pw + l15 * 264 + kt * 32 + q4 * 8);
#pragma unroll
        for (int dt = 0; dt < 4; ++dt) {
          s16x8 bv = *(const s16x8*)(vt + (dt * 16 + l15) * 264 + kt * 32 + q4 * 8);
          oc[dt] = __builtin_amdgcn_mfma_f32_16x16x32_bf16(ap, bv, oc[dt], 0, 0, 0);
        }
      }
    }
    __builtin_amdgcn_s_setprio(0);

    float inv[4];
#pragma unroll
    for (int r = 0; r < 4; ++r) inv[r] = 1.0f / lrow[r];

    // normalize, stage O tile (16 rows x 64 cols) in per-wave LDS, then b128 coalesced stores
#pragma unroll
    for (int dt = 0; dt < 4; ++dt)
#pragma unroll
      for (int r = 0; r < 4; ++r)
        pw[(q4 * 4 + r) * 264 + dt * 16 + l15] = f2bf(oc[dt][r] * inv[r]);
#pragma unroll
    for (int k = 0; k < 2; ++k) {
      int c2 = k * 64 + lane;
      int row = c2 >> 3, c8 = (c2 & 7) * 8;
      u16x8 v = *(const u16x8*)(pw + row * 264 + c8);
      *(u16x8*)(Ob + (size_t)(r0 + row) * D_MODEL + c8) = v;
    }
  }
}

extern "C" void kernel_launch(void* const* d_in, const int* in_sizes, int n_in,
                              void* d_out, int out_size, void* d_ws, size_t ws_size,
                              hipStream_t stream) {
  const float* x  = (const float*)d_in[0];
  const float* Wq = (const float*)d_in[1];
  const float* bq = (const float*)d_in[2];
  const float* Wk = (const float*)d_in[3];
  const float* bk = (const float*)d_in[4];
  const float* Wv = (const float*)d_in[5];
  const float* bv = (const float*)d_in[6];
  const float* Wo = (const float*)d_in[7];
  const float* bo = (const float*)d_in[8];
  float* out = (float*)d_out;

  // ws (bf16 internal): Wt 4x1M, xb 16M, Q/K/V 16M each. O aliases Q. Total 136 MB.
  u16* ws = (u16*)d_ws;
  u16* Wt = ws;
  u16* Xb = ws + (size_t)4 * 1048576;
  u16* Qw = Xb + (size_t)16777216;
  u16* Kw = Qw + (size_t)16777216;
  u16* Vw = Kw + (size_t)16777216;
  u16* Ow = Qw;   // alias

  cast_x<<<dim3(8192), 256, 0, stream>>>(x, Xb);
  transpose_w<<<dim3(16, 16, 4), 256, 0, stream>>>(Wq, Wk, Wv, Wo, Wt);
  // QKV: M=16384, N=3072 -> 64 x 12 = 768 blocks (768 % 8 == 0)
  gemm8<0, 12><<<dim3(768), 512, 0, stream>>>(Xb, Wt, bq, bk, bv, Qw, Kw, Vw);
  attn<<<dim3(64 * 16), 128, 0, stream>>>(Qw, Kw, Vw, Ow);
  // O-proj: M=16384, N=1024 -> 64 x 4 = 256 blocks
  gemm8<1, 4><<<dim3(256), 512, 0, stream>>>(Ow, Wt + (size_t)3 * 1048576, bo,
                                             nullptr, nullptr, out, nullptr, nullptr);
}